// Round 14
// baseline (137.116 us; speedup 1.0000x reference)
//
#include <hip/hip_runtime.h>
#include <math.h>

// ---------------------------------------------------------------------------
// Attention_2010044694851: x[4,2048,1024] fp32, w_qkv[1536,1024], w_out[1024,512],
// b_out[1024] -> out[4,2048,1024] fp32.
// cvt(all) -> QKV GEMM (256x192 8-phase, V^T epi) -> causal sim GEMM
// (128x64, aspect-2 triangular grid, 4 blk/CU) -> softmax -> PV GEMM
// (64x64, 6 blk/CU, longest-K first) -> proj GEMM (256x128 8-phase).
// R13 lesson: 8-phase needs nkt>=16 (proj at nkt=8 = parity). R14: raise
// 2-phase-core occupancy via smaller sim/PV tiles (m97 3+/CU overlap regime).
// ---------------------------------------------------------------------------

typedef __attribute__((ext_vector_type(8))) short bf16x8_t;
typedef __attribute__((ext_vector_type(4))) float f32x4_t;

__device__ __forceinline__ unsigned short f2bf(float f) {
  unsigned int u = __float_as_uint(f);
  u = (u + 0x7FFFu + ((u >> 16) & 1u)) >> 16;
  return (unsigned short)u;
}
__device__ __forceinline__ float bf2f(unsigned short h) {
  return __uint_as_float(((unsigned int)h) << 16);
}

template <int N>
__device__ __forceinline__ void wait_vmcnt() {
  if constexpr (N == 0) asm volatile("s_waitcnt vmcnt(0)" ::: "memory");
  else if constexpr (N == 2) asm volatile("s_waitcnt vmcnt(2)" ::: "memory");
  else if constexpr (N == 3) asm volatile("s_waitcnt vmcnt(3)" ::: "memory");
  else if constexpr (N == 4) asm volatile("s_waitcnt vmcnt(4)" ::: "memory");
  else if constexpr (N == 6) asm volatile("s_waitcnt vmcnt(6)" ::: "memory");
}
__device__ __forceinline__ void bar_fence() {
  asm volatile("s_barrier" ::: "memory");
}
__device__ __forceinline__ void lgkm0() {
  asm volatile("s_waitcnt lgkmcnt(0)" ::: "memory");
}

// ---------------------------------------------------------------------------
__global__ __launch_bounds__(256) void cvt_all(
    const float* __restrict__ x, unsigned short* __restrict__ xb, int nx,
    const float* __restrict__ w1, unsigned short* __restrict__ w1b, int n1,
    const float* __restrict__ w2, unsigned short* __restrict__ w2b, int n2) {
  const int stride = gridDim.x * blockDim.x * 4;
  const int t0 = (blockIdx.x * blockDim.x + threadIdx.x) * 4;
  for (int i = t0; i < nx; i += stride) {
    float4 f = *(const float4*)(x + i);
    ushort4 u;
    u.x = f2bf(f.x); u.y = f2bf(f.y); u.z = f2bf(f.z); u.w = f2bf(f.w);
    *(ushort4*)(xb + i) = u;
  }
  for (int i = t0; i < n1; i += stride) {
    float4 f = *(const float4*)(w1 + i);
    ushort4 u;
    u.x = f2bf(f.x); u.y = f2bf(f.y); u.z = f2bf(f.z); u.w = f2bf(f.w);
    *(ushort4*)(w1b + i) = u;
  }
  for (int i = t0; i < n2; i += stride) {
    float4 f = *(const float4*)(w2 + i);
    ushort4 u;
    u.x = f2bf(f.x); u.y = f2bf(f.y); u.z = f2bf(f.z); u.w = f2bf(f.w);
    *(ushort4*)(w2b + i) = u;
  }
}

// ---------------------------------------------------------------------------
__global__ __launch_bounds__(256) void softmax_causal(unsigned short* __restrict__ sim) {
  const int lane = threadIdx.x & 63;
  const int rowg = blockIdx.x * 4 + (threadIdx.x >> 6);
  const int i = rowg & 2047;
  unsigned short* row = sim + (size_t)rowg * 2048;
  const int nv = i + 1;
  const int tb = ((i >> 6) + 1) << 6;
  const int nc = (nv + 255) >> 8;
  const int ns = (tb + 255) >> 8;

  float v[32];
  float m = -1e30f;
#pragma unroll
  for (int c = 0; c < 8; ++c) {
    if (c < nc) {
      const int j0 = c * 256 + lane * 4;
      ushort4 u = *(const ushort4*)(row + j0);
      float f0 = bf2f(u.x), f1 = bf2f(u.y), f2 = bf2f(u.z), f3 = bf2f(u.w);
      v[c * 4 + 0] = (j0 + 0 < nv) ? f0 : -1e30f;
      v[c * 4 + 1] = (j0 + 1 < nv) ? f1 : -1e30f;
      v[c * 4 + 2] = (j0 + 2 < nv) ? f2 : -1e30f;
      v[c * 4 + 3] = (j0 + 3 < nv) ? f3 : -1e30f;
      m = fmaxf(m, fmaxf(fmaxf(v[c * 4], v[c * 4 + 1]), fmaxf(v[c * 4 + 2], v[c * 4 + 3])));
    }
  }
#pragma unroll
  for (int s = 32; s >= 1; s >>= 1) m = fmaxf(m, __shfl_xor(m, s));
  float sum = 0.f;
#pragma unroll
  for (int c = 0; c < 8; ++c) {
    if (c < nc) {
#pragma unroll
      for (int e = 0; e < 4; ++e) {
        float p = __expf(v[c * 4 + e] - m);
        v[c * 4 + e] = p;
        sum += p;
      }
    }
  }
#pragma unroll
  for (int s = 32; s >= 1; s >>= 1) sum += __shfl_xor(sum, s);
  const float inv = 1.0f / sum;
#pragma unroll
  for (int c = 0; c < 8; ++c) {
    if (c < ns) {
      const int j0 = c * 256 + lane * 4;
      ushort4 u;
      if (c < nc) {
        u.x = f2bf(v[c * 4 + 0] * inv);
        u.y = f2bf(v[c * 4 + 1] * inv);
        u.z = f2bf(v[c * 4 + 2] * inv);
        u.w = f2bf(v[c * 4 + 3] * inv);
      } else {
        u.x = u.y = u.z = u.w = 0;
      }
      *(ushort4*)(row + j0) = u;
    }
  }
}

// ---------------------------------------------------------------------------
// 8-phase 256xBN8 GEMM engine (R11/R12-verified ledger).
// EPI8 0: QKV scatter (q*scale | k | V^T).  1: proj fp32 + bias.
// ---------------------------------------------------------------------------
template <int EPI8, int BN8, int K8>
__global__ __launch_bounds__(512, 1) void gemm8(
    const unsigned short* __restrict__ A, const unsigned short* __restrict__ B,
    void* __restrict__ O0, void* __restrict__ O1, void* __restrict__ O2,
    const float* __restrict__ bias, float qscale) {
  constexpr int nkt = K8 / 64;
  constexpr int FNW = BN8 / 64;
  constexpr int BL = BN8 / 64;
  constexpr int BBYTES = BN8 * 128;
  extern __shared__ char smem[];
  const int bm = blockIdx.x, bn = blockIdx.y;
  const int tid = threadIdx.x, lane = tid & 63, wave = tid >> 6;
  const int wm = wave >> 2, wn = wave & 3;

  const char* Ag = (const char*)(A + (size_t)bm * 256 * K8);
  const char* Bg = (const char*)(B + (size_t)bn * BN8 * K8);

  auto stageA = [&](char* buf, int t, int h) {
#pragma unroll
    for (int j = 0; j < 2; ++j) {
      const int o = h * 16384 + j * 8192 + tid * 16;
      const int r = o >> 7;
      const int ls = ((o >> 4) & 7) ^ (r & 7);
      __builtin_amdgcn_global_load_lds(
          (const __attribute__((address_space(1))) void*)(
              Ag + (size_t)r * (K8 * 2) + t * 128 + ls * 16),
          (__attribute__((address_space(3))) void*)(buf + o), 16, 0, 0);
    }
  };
  auto stageB = [&](char* buf, int t) {
#pragma unroll
    for (int j = 0; j < BL; ++j) {
      const int o = j * 8192 + tid * 16;
      const int r = o >> 7;
      const int ls = ((o >> 4) & 7) ^ (r & 7);
      __builtin_amdgcn_global_load_lds(
          (const __attribute__((address_space(1))) void*)(
              Bg + (size_t)r * (K8 * 2) + t * 128 + ls * 16),
          (__attribute__((address_space(3))) void*)(buf + o), 16, 0, 0);
    }
  };
  auto rdA = [&](const char* buf, int fi, int ks) -> bf16x8_t {
    const int row = wm * 128 + fi * 16 + (lane & 15);
    const int sl = ((ks << 2) + (lane >> 4)) ^ (row & 7);
    return *(const bf16x8_t*)(buf + row * 128 + sl * 16);
  };
  auto rdB = [&](const char* buf, int fj, int ks) -> bf16x8_t {
    const int row = wn * (BN8 / 4) + fj * 16 + (lane & 15);
    const int sl = ((ks << 2) + (lane >> 4)) ^ (row & 7);
    return *(const bf16x8_t*)(buf + row * 128 + sl * 16);
  };

  f32x4_t acc[8][FNW] = {};
  bf16x8_t bv[FNW][2];

  stageB(smem + 65536, 0);
  stageA(smem, 0, 0); stageA(smem, 0, 1);
  stageB(smem + 65536 + BBYTES, 1);
  wait_vmcnt<BL>();
  bar_fence();

  for (int t = 0; t < nkt; ++t) {
    char* Ac = smem + (t & 1) * 32768;
    char* Bc = smem + 65536 + (t & 1) * BBYTES;
    char* An = smem + ((t & 1) ^ 1) * 32768;
    bf16x8_t av[2][2];

#pragma unroll
    for (int fj = 0; fj < FNW; ++fj)
#pragma unroll
      for (int ks = 0; ks < 2; ++ks) bv[fj][ks] = rdB(Bc, fj, ks);
#pragma unroll
    for (int i = 0; i < 2; ++i)
#pragma unroll
      for (int ks = 0; ks < 2; ++ks) av[i][ks] = rdA(Ac, i, ks);
    if (t + 1 < nkt) stageA(An, t + 1, 0);
    bar_fence();
    lgkm0();
    __builtin_amdgcn_s_setprio(1);
#pragma unroll
    for (int i = 0; i < 2; ++i)
#pragma unroll
      for (int fj = 0; fj < FNW; ++fj)
#pragma unroll
        for (int ks = 0; ks < 2; ++ks)
          acc[i][fj] = __builtin_amdgcn_mfma_f32_16x16x32_bf16(av[i][ks], bv[fj][ks], acc[i][fj], 0, 0, 0);
    __builtin_amdgcn_s_setprio(0);
    bar_fence();

#pragma unroll
    for (int i = 0; i < 2; ++i)
#pragma unroll
      for (int ks = 0; ks < 2; ++ks) av[i][ks] = rdA(Ac, 2 + i, ks);
    if (t + 1 < nkt) stageA(An, t + 1, 1);
    bar_fence();
    lgkm0();
    __builtin_amdgcn_s_setprio(1);
#pragma unroll
    for (int i = 0; i < 2; ++i)
#pragma unroll
      for (int fj = 0; fj < FNW; ++fj)
#pragma unroll
        for (int ks = 0; ks < 2; ++ks)
          acc[2 + i][fj] = __builtin_amdgcn_mfma_f32_16x16x32_bf16(av[i][ks], bv[fj][ks], acc[2 + i][fj], 0, 0, 0);
    __builtin_amdgcn_s_setprio(0);
    bar_fence();

#pragma unroll
    for (int i = 0; i < 2; ++i)
#pragma unroll
      for (int ks = 0; ks < 2; ++ks) av[i][ks] = rdA(Ac, 4 + i, ks);
    if (t + 2 < nkt) stageB(Bc, t + 2);
    bar_fence();
    lgkm0();
    __builtin_amdgcn_s_setprio(1);
#pragma unroll
    for (int i = 0; i < 2; ++i)
#pragma unroll
      for (int fj = 0; fj < FNW; ++fj)
#pragma unroll
        for (int ks = 0; ks < 2; ++ks)
          acc[4 + i][fj] = __builtin_amdgcn_mfma_f32_16x16x32_bf16(av[i][ks], bv[fj][ks], acc[4 + i][fj], 0, 0, 0);
    __builtin_amdgcn_s_setprio(0);
    bar_fence();

#pragma unroll
    for (int i = 0; i < 2; ++i)
#pragma unroll
      for (int ks = 0; ks < 2; ++ks) av[i][ks] = rdA(Ac, 6 + i, ks);
    if (t + 1 < nkt) {
      if (t + 2 < nkt) wait_vmcnt<BL>();
      else wait_vmcnt<0>();
    }
    bar_fence();
    lgkm0();
    __builtin_amdgcn_s_setprio(1);
#pragma unroll
    for (int i = 0; i < 2; ++i)
#pragma unroll
      for (int fj = 0; fj < FNW; ++fj)
#pragma unroll
        for (int ks = 0; ks < 2; ++ks)
          acc[6 + i][fj] = __builtin_amdgcn_mfma_f32_16x16x32_bf16(av[i][ks], bv[fj][ks], acc[6 + i][fj], 0, 0, 0);
    __builtin_amdgcn_s_setprio(0);
    bar_fence();
  }

#pragma unroll
  for (int fi = 0; fi < 8; ++fi) {
    const int row0 = bm * 256 + wm * 128 + fi * 16 + ((lane >> 4) << 2);
#pragma unroll
    for (int fj = 0; fj < FNW; ++fj) {
      const int col = bn * BN8 + wn * (BN8 / 4) + fj * 16 + (lane & 15);
      if constexpr (EPI8 == 0) {
        if (col < 512) {
#pragma unroll
          for (int r = 0; r < 4; ++r)
            ((unsigned short*)O0)[(size_t)(row0 + r) * 512 + col] =
                f2bf(acc[fi][fj][r] * qscale);
        } else if (col < 1024) {
#pragma unroll
          for (int r = 0; r < 4; ++r)
            ((unsigned short*)O1)[(size_t)(row0 + r) * 512 + (col - 512)] =
                f2bf(acc[fi][fj][r]);
        } else {
          const int e = col - 1024;
          const int b = row0 >> 11, n0 = row0 & 2047;
          ushort4 u;
          u.x = f2bf(acc[fi][fj][0]);
          u.y = f2bf(acc[fi][fj][1]);
          u.z = f2bf(acc[fi][fj][2]);
          u.w = f2bf(acc[fi][fj][3]);
          *(ushort4*)((unsigned short*)O2 + ((size_t)b * 512 + e) * 2048 + n0) = u;
        }
      } else {
        const float bb = bias[col];
#pragma unroll
        for (int r = 0; r < 4; ++r)
          ((float*)O0)[(size_t)(row0 + r) * 1024 + col] = acc[fi][fj][r] + bb;
      }
    }
  }
}

// ---------------------------------------------------------------------------
// bf16 B^T GEMM (R6-proven 2-phase core): C[M,N] = A[M,K] * B[N,K]^T.
// EPI: 1 sim bf16  2 attn-out bf16.
// TRI: aspect-2 packed triangle (BMxBN = 128x64): per batch m in [0,16),
//      n in [0, 2m+2); bid' range [m^2+m, m^2+3m+2). z = blockIdx.y.
// REV: reverse bm (longest-K first when klim).
// ---------------------------------------------------------------------------
template <int EPI, int BM, int BN, int REV, int TRI>
__global__ __launch_bounds__(256) void gemm_bt(
    const unsigned short* __restrict__ A, const unsigned short* __restrict__ B,
    int M, int N, int K, long strideA, long strideB, int klim,
    void* __restrict__ O0, const float* __restrict__ bias) {
  int bm, bn, bz;
  if constexpr (TRI) {
    const int bid = blockIdx.x;
    bm = (int)sqrtf((float)bid);
    while ((bm + 1) * (bm + 2) <= bid) ++bm;
    while (bm * (bm + 1) > bid) --bm;
    bn = bid - bm * (bm + 1);
    bz = blockIdx.y;
  } else {
    bm = REV ? (gridDim.x - 1 - blockIdx.x) : blockIdx.x;
    bn = blockIdx.y;
    bz = blockIdx.z;
  }
  const int tid = threadIdx.x, lane = tid & 63, wave = tid >> 6;
  const int wr = wave >> 1, wc = wave & 1;
  constexpr int FM = BM / 32, FN = BN / 32;
  constexpr int AR = BM / 64, BR = BN / 64;
  constexpr int L = AR + BR;

  __shared__ alignas(16) unsigned short As[3][BM * 32];
  __shared__ alignas(16) unsigned short Bs[3][BN * 32];

  const unsigned short* Ab = A + (size_t)bz * strideA + (size_t)bm * BM * K;
  const unsigned short* Bb = B + (size_t)bz * strideB + (size_t)bn * BN * K;

  const int kmax = klim ? min(K, (bm + 1) * BM) : K;
  const int nkt = kmax >> 5;

  auto stage = [&](int buf, int kt) {
    const int loff = tid * 16;
#pragma unroll
    for (int i = 0; i < AR; ++i) {
      const int o = i * 4096 + loff;
      const int r = o >> 6;
      const int sl = ((o >> 4) & 3) ^ ((r >> 1) & 3);
      __builtin_amdgcn_global_load_lds(
          (const __attribute__((address_space(1))) void*)(
              (const char*)(Ab + (size_t)r * K) + (size_t)kt * 64 + sl * 16),
          (__attribute__((address_space(3))) void*)((char*)As[buf] + o), 16, 0, 0);
    }
#pragma unroll
    for (int i = 0; i < BR; ++i) {
      const int o = i * 4096 + loff;
      const int r = o >> 6;
      const int sl = ((o >> 4) & 3) ^ ((r >> 1) & 3);
      __builtin_amdgcn_global_load_lds(
          (const __attribute__((address_space(1))) void*)(
              (const char*)(Bb + (size_t)r * K) + (size_t)kt * 64 + sl * 16),
          (__attribute__((address_space(3))) void*)((char*)Bs[buf] + o), 16, 0, 0);
    }
  };

  f32x4_t acc[FM][FN] = {};

  stage(0, 0);
  if (nkt > 1) stage(1, 1);
  int cur = 0;
  for (int kt = 0; kt < nkt; ++kt) {
    if (kt + 1 < nkt) wait_vmcnt<L>();
    else wait_vmcnt<0>();
    __builtin_amdgcn_s_barrier();

    bf16x8_t av[FM], bv[FN];
#pragma unroll
    for (int f = 0; f < FM; ++f) {
      const int row = wr * (BM / 2) + f * 16 + (lane & 15);
      const int sp = (lane >> 4) ^ ((row >> 1) & 3);
      av[f] = *(const bf16x8_t*)((const char*)As[cur] + row * 64 + sp * 16);
    }
#pragma unroll
    for (int f = 0; f < FN; ++f) {
      const int row = wc * (BN / 2) + f * 16 + (lane & 15);
      const int sp = (lane >> 4) ^ ((row >> 1) & 3);
      bv[f] = *(const bf16x8_t*)((const char*)Bs[cur] + row * 64 + sp * 16);
    }
    if (kt + 2 < nkt) {
      int nb = cur + 2;
      if (nb >= 3) nb -= 3;
      stage(nb, kt + 2);
    }
    __builtin_amdgcn_s_setprio(1);
#pragma unroll
    for (int fi = 0; fi < FM; ++fi)
#pragma unroll
      for (int fj = 0; fj < FN; ++fj)
        acc[fi][fj] = __builtin_amdgcn_mfma_f32_16x16x32_bf16(av[fi], bv[fj], acc[fi][fj], 0, 0, 0);
    __builtin_amdgcn_s_setprio(0);
    cur = (cur + 1 == 3) ? 0 : cur + 1;
  }

#pragma unroll
  for (int fi = 0; fi < FM; ++fi) {
    const int row_l = wr * (BM / 2) + fi * 16 + ((lane >> 4) << 2);
#pragma unroll
    for (int fj = 0; fj < FN; ++fj) {
      const int col = bn * BN + wc * (BN / 2) + fj * 16 + (lane & 15);
#pragma unroll
      for (int r = 0; r < 4; ++r) {
        const int row = bm * BM + row_l + r;
        float v = acc[fi][fj][r];
        if constexpr (EPI == 1) {
          ((unsigned short*)O0)[(size_t)bz * 2048 * 2048 + (size_t)row * 2048 + col] = f2bf(v);
        } else {
          ((unsigned short*)O0)[(size_t)bz * 2048 * 512 + (size_t)row * 512 + col] = f2bf(v);
        }
      }
    }
  }
}

// ---------------------------------------------------------------------------
extern "C" void kernel_launch(void* const* d_in, const int* in_sizes, int n_in,
                              void* d_out, int out_size, void* d_ws, size_t ws_size,
                              hipStream_t stream) {
  const float* x = (const float*)d_in[0];
  const float* w_qkv = (const float*)d_in[1];
  const float* w_out = (const float*)d_in[2];
  const float* b_out = (const float*)d_in[3];
  float* out = (float*)d_out;

  char* ws = (char*)d_ws;
  size_t off = 0;
  auto alloc = [&](size_t bytes) {
    size_t o = off;
    off += (bytes + 255) & ~(size_t)255;
    return o;
  };
  unsigned short* xb = (unsigned short*)(ws + alloc((size_t)8192 * 1024 * 2));
  unsigned short* wqkvb = (unsigned short*)(ws + alloc((size_t)1536 * 1024 * 2));
  unsigned short* woutb = (unsigned short*)(ws + alloc((size_t)1024 * 512 * 2));
  unsigned short* qb = (unsigned short*)(ws + alloc((size_t)8192 * 512 * 2));
  unsigned short* kb = (unsigned short*)(ws + alloc((size_t)8192 * 512 * 2));
  unsigned short* vtb = (unsigned short*)(ws + alloc((size_t)8192 * 512 * 2));
  unsigned short* sim = (unsigned short*)(ws + alloc((size_t)4 * 2048 * 2048 * 2));
  unsigned short* ao = (unsigned short*)(ws + alloc((size_t)8192 * 512 * 2));

  const float scale = 1.0f / sqrtf(512.0f);

  cvt_all<<<2048, 256, 0, stream>>>(x, xb, 8192 * 1024, w_qkv, wqkvb, 1536 * 1024,
                                    w_out, woutb, 1024 * 512);

  // QKV: 256x192 8-phase, 32x8 = 256 blocks (1/CU), 112KB LDS; V^T epilogue.
  gemm8<0, 192, 1024><<<dim3(32, 8), 512, 65536 + 2 * 192 * 128, stream>>>(
      xb, wqkvb, qb, kb, vtb, nullptr, scale);

  // sim = q*scale @ k^T — 128x64 tiles, aspect-2 packed triangle:
  // 272 tiles/batch x 4 = 1088 blocks (36KB LDS -> 4 blocks/CU).
  gemm_bt<1, 128, 64, 0, 1><<<dim3(272, 4, 1), 256, 0, stream>>>(
      qb, kb, 2048, 2048, 512, (long)2048 * 512, (long)2048 * 512,
      0, sim, nullptr);

  softmax_causal<<<2048, 256, 0, stream>>>(sim);

  // attn @ v : 64x64 tiles (24KB LDS -> 6 blocks/CU), 1024 blocks,
  // 64-granular K limit, longest-K first.
  gemm_bt<2, 64, 64, 1, 0><<<dim3(32, 8, 4), 256, 0, stream>>>(
      sim, vtb, 2048, 512, 2048, (long)2048 * 2048, (long)512 * 2048,
      1, ao, nullptr);

  // proj: 256x128 8-phase, 32x8 = 256 blocks (1/CU), 96KB LDS, fp32+bias.
  gemm8<1, 128, 512><<<dim3(32, 8), 512, 65536 + 2 * 128 * 128, stream>>>(
      ao, woutb, out, nullptr, nullptr, b_out, 0.f);
}

// Round 15
// 127.388 us; speedup vs baseline: 1.0764x; 1.0764x over previous
//
#include <hip/hip_runtime.h>
#include <math.h>

// ---------------------------------------------------------------------------
// Attention_2010044694851: x[4,2048,1024] fp32, w_qkv[1536,1024], w_out[1024,512],
// b_out[1024] -> out[4,2048,1024] fp32.
// cvt(all) -> QKV GEMM (256x192 8-phase, V^T epi) -> causal sim GEMM
// (triangular, 2-phase core) -> softmax -> PV GEMM (64x128) -> proj GEMM
// (256x128 8-phase).  == R13 best-verified configuration (127.5µs) ==
// R14 lesson: smaller sim/PV tiles -> 2x A-refetch -> net loss (FETCH 37.6MB,
// MfmaUtil 7%). Occupancy gains cannot pay for operand re-read multiplication.
// ---------------------------------------------------------------------------

typedef __attribute__((ext_vector_type(8))) short bf16x8_t;
typedef __attribute__((ext_vector_type(4))) float f32x4_t;

__device__ __forceinline__ unsigned short f2bf(float f) {
  unsigned int u = __float_as_uint(f);
  u = (u + 0x7FFFu + ((u >> 16) & 1u)) >> 16;
  return (unsigned short)u;
}
__device__ __forceinline__ float bf2f(unsigned short h) {
  return __uint_as_float(((unsigned int)h) << 16);
}

template <int N>
__device__ __forceinline__ void wait_vmcnt() {
  if constexpr (N == 0) asm volatile("s_waitcnt vmcnt(0)" ::: "memory");
  else if constexpr (N == 2) asm volatile("s_waitcnt vmcnt(2)" ::: "memory");
  else if constexpr (N == 3) asm volatile("s_waitcnt vmcnt(3)" ::: "memory");
  else if constexpr (N == 4) asm volatile("s_waitcnt vmcnt(4)" ::: "memory");
  else if constexpr (N == 6) asm volatile("s_waitcnt vmcnt(6)" ::: "memory");
}
__device__ __forceinline__ void bar_fence() {
  asm volatile("s_barrier" ::: "memory");
}
__device__ __forceinline__ void lgkm0() {
  asm volatile("s_waitcnt lgkmcnt(0)" ::: "memory");
}

// ---------------------------------------------------------------------------
__global__ __launch_bounds__(256) void cvt_all(
    const float* __restrict__ x, unsigned short* __restrict__ xb, int nx,
    const float* __restrict__ w1, unsigned short* __restrict__ w1b, int n1,
    const float* __restrict__ w2, unsigned short* __restrict__ w2b, int n2) {
  const int stride = gridDim.x * blockDim.x * 4;
  const int t0 = (blockIdx.x * blockDim.x + threadIdx.x) * 4;
  for (int i = t0; i < nx; i += stride) {
    float4 f = *(const float4*)(x + i);
    ushort4 u;
    u.x = f2bf(f.x); u.y = f2bf(f.y); u.z = f2bf(f.z); u.w = f2bf(f.w);
    *(ushort4*)(xb + i) = u;
  }
  for (int i = t0; i < n1; i += stride) {
    float4 f = *(const float4*)(w1 + i);
    ushort4 u;
    u.x = f2bf(f.x); u.y = f2bf(f.y); u.z = f2bf(f.z); u.w = f2bf(f.w);
    *(ushort4*)(w1b + i) = u;
  }
  for (int i = t0; i < n2; i += stride) {
    float4 f = *(const float4*)(w2 + i);
    ushort4 u;
    u.x = f2bf(f.x); u.y = f2bf(f.y); u.z = f2bf(f.z); u.w = f2bf(f.w);
    *(ushort4*)(w2b + i) = u;
  }
}

// ---------------------------------------------------------------------------
__global__ __launch_bounds__(256) void softmax_causal(unsigned short* __restrict__ sim) {
  const int lane = threadIdx.x & 63;
  const int rowg = blockIdx.x * 4 + (threadIdx.x >> 6);
  const int i = rowg & 2047;
  unsigned short* row = sim + (size_t)rowg * 2048;
  const int nv = i + 1;
  const int tb = ((i >> 6) + 1) << 6;
  const int nc = (nv + 255) >> 8;
  const int ns = (tb + 255) >> 8;

  float v[32];
  float m = -1e30f;
#pragma unroll
  for (int c = 0; c < 8; ++c) {
    if (c < nc) {
      const int j0 = c * 256 + lane * 4;
      ushort4 u = *(const ushort4*)(row + j0);
      float f0 = bf2f(u.x), f1 = bf2f(u.y), f2 = bf2f(u.z), f3 = bf2f(u.w);
      v[c * 4 + 0] = (j0 + 0 < nv) ? f0 : -1e30f;
      v[c * 4 + 1] = (j0 + 1 < nv) ? f1 : -1e30f;
      v[c * 4 + 2] = (j0 + 2 < nv) ? f2 : -1e30f;
      v[c * 4 + 3] = (j0 + 3 < nv) ? f3 : -1e30f;
      m = fmaxf(m, fmaxf(fmaxf(v[c * 4], v[c * 4 + 1]), fmaxf(v[c * 4 + 2], v[c * 4 + 3])));
    }
  }
#pragma unroll
  for (int s = 32; s >= 1; s >>= 1) m = fmaxf(m, __shfl_xor(m, s));
  float sum = 0.f;
#pragma unroll
  for (int c = 0; c < 8; ++c) {
    if (c < nc) {
#pragma unroll
      for (int e = 0; e < 4; ++e) {
        float p = __expf(v[c * 4 + e] - m);
        v[c * 4 + e] = p;
        sum += p;
      }
    }
  }
#pragma unroll
  for (int s = 32; s >= 1; s >>= 1) sum += __shfl_xor(sum, s);
  const float inv = 1.0f / sum;
#pragma unroll
  for (int c = 0; c < 8; ++c) {
    if (c < ns) {
      const int j0 = c * 256 + lane * 4;
      ushort4 u;
      if (c < nc) {
        u.x = f2bf(v[c * 4 + 0] * inv);
        u.y = f2bf(v[c * 4 + 1] * inv);
        u.z = f2bf(v[c * 4 + 2] * inv);
        u.w = f2bf(v[c * 4 + 3] * inv);
      } else {
        u.x = u.y = u.z = u.w = 0;
      }
      *(ushort4*)(row + j0) = u;
    }
  }
}

// ---------------------------------------------------------------------------
// 8-phase 256xBN8 GEMM engine (R11/R12-verified ledger, 3.24 TF/CU):
//   - B-frags reg-cached at ph0 => B buffer overwritable at ph2
//   - stage A(t+1) ph0/ph1 (other parity buf), B(t+2) full-tile at ph2
//   - ph3: vmcnt(B-loads) -> oldest A(t+1) drained, FIFO covers B(t+1)
// EPI8 0: QKV scatter (q*scale | k | V^T).  1: proj fp32 + bias.
// ---------------------------------------------------------------------------
template <int EPI8, int BN8, int K8>
__global__ __launch_bounds__(512, 1) void gemm8(
    const unsigned short* __restrict__ A, const unsigned short* __restrict__ B,
    void* __restrict__ O0, void* __restrict__ O1, void* __restrict__ O2,
    const float* __restrict__ bias, float qscale) {
  constexpr int nkt = K8 / 64;
  constexpr int FNW = BN8 / 64;
  constexpr int BL = BN8 / 64;
  constexpr int BBYTES = BN8 * 128;
  extern __shared__ char smem[];
  const int bm = blockIdx.x, bn = blockIdx.y;
  const int tid = threadIdx.x, lane = tid & 63, wave = tid >> 6;
  const int wm = wave >> 2, wn = wave & 3;

  const char* Ag = (const char*)(A + (size_t)bm * 256 * K8);
  const char* Bg = (const char*)(B + (size_t)bn * BN8 * K8);

  auto stageA = [&](char* buf, int t, int h) {
#pragma unroll
    for (int j = 0; j < 2; ++j) {
      const int o = h * 16384 + j * 8192 + tid * 16;
      const int r = o >> 7;
      const int ls = ((o >> 4) & 7) ^ (r & 7);
      __builtin_amdgcn_global_load_lds(
          (const __attribute__((address_space(1))) void*)(
              Ag + (size_t)r * (K8 * 2) + t * 128 + ls * 16),
          (__attribute__((address_space(3))) void*)(buf + o), 16, 0, 0);
    }
  };
  auto stageB = [&](char* buf, int t) {
#pragma unroll
    for (int j = 0; j < BL; ++j) {
      const int o = j * 8192 + tid * 16;
      const int r = o >> 7;
      const int ls = ((o >> 4) & 7) ^ (r & 7);
      __builtin_amdgcn_global_load_lds(
          (const __attribute__((address_space(1))) void*)(
              Bg + (size_t)r * (K8 * 2) + t * 128 + ls * 16),
          (__attribute__((address_space(3))) void*)(buf + o), 16, 0, 0);
    }
  };
  auto rdA = [&](const char* buf, int fi, int ks) -> bf16x8_t {
    const int row = wm * 128 + fi * 16 + (lane & 15);
    const int sl = ((ks << 2) + (lane >> 4)) ^ (row & 7);
    return *(const bf16x8_t*)(buf + row * 128 + sl * 16);
  };
  auto rdB = [&](const char* buf, int fj, int ks) -> bf16x8_t {
    const int row = wn * (BN8 / 4) + fj * 16 + (lane & 15);
    const int sl = ((ks << 2) + (lane >> 4)) ^ (row & 7);
    return *(const bf16x8_t*)(buf + row * 128 + sl * 16);
  };

  f32x4_t acc[8][FNW] = {};
  bf16x8_t bv[FNW][2];

  stageB(smem + 65536, 0);
  stageA(smem, 0, 0); stageA(smem, 0, 1);
  stageB(smem + 65536 + BBYTES, 1);
  wait_vmcnt<BL>();
  bar_fence();

  for (int t = 0; t < nkt; ++t) {
    char* Ac = smem + (t & 1) * 32768;
    char* Bc = smem + 65536 + (t & 1) * BBYTES;
    char* An = smem + ((t & 1) ^ 1) * 32768;
    bf16x8_t av[2][2];

#pragma unroll
    for (int fj = 0; fj < FNW; ++fj)
#pragma unroll
      for (int ks = 0; ks < 2; ++ks) bv[fj][ks] = rdB(Bc, fj, ks);
#pragma unroll
    for (int i = 0; i < 2; ++i)
#pragma unroll
      for (int ks = 0; ks < 2; ++ks) av[i][ks] = rdA(Ac, i, ks);
    if (t + 1 < nkt) stageA(An, t + 1, 0);
    bar_fence();
    lgkm0();
    __builtin_amdgcn_s_setprio(1);
#pragma unroll
    for (int i = 0; i < 2; ++i)
#pragma unroll
      for (int fj = 0; fj < FNW; ++fj)
#pragma unroll
        for (int ks = 0; ks < 2; ++ks)
          acc[i][fj] = __builtin_amdgcn_mfma_f32_16x16x32_bf16(av[i][ks], bv[fj][ks], acc[i][fj], 0, 0, 0);
    __builtin_amdgcn_s_setprio(0);
    bar_fence();

#pragma unroll
    for (int i = 0; i < 2; ++i)
#pragma unroll
      for (int ks = 0; ks < 2; ++ks) av[i][ks] = rdA(Ac, 2 + i, ks);
    if (t + 1 < nkt) stageA(An, t + 1, 1);
    bar_fence();
    lgkm0();
    __builtin_amdgcn_s_setprio(1);
#pragma unroll
    for (int i = 0; i < 2; ++i)
#pragma unroll
      for (int fj = 0; fj < FNW; ++fj)
#pragma unroll
        for (int ks = 0; ks < 2; ++ks)
          acc[2 + i][fj] = __builtin_amdgcn_mfma_f32_16x16x32_bf16(av[i][ks], bv[fj][ks], acc[2 + i][fj], 0, 0, 0);
    __builtin_amdgcn_s_setprio(0);
    bar_fence();

#pragma unroll
    for (int i = 0; i < 2; ++i)
#pragma unroll
      for (int ks = 0; ks < 2; ++ks) av[i][ks] = rdA(Ac, 4 + i, ks);
    if (t + 2 < nkt) stageB(Bc, t + 2);
    bar_fence();
    lgkm0();
    __builtin_amdgcn_s_setprio(1);
#pragma unroll
    for (int i = 0; i < 2; ++i)
#pragma unroll
      for (int fj = 0; fj < FNW; ++fj)
#pragma unroll
        for (int ks = 0; ks < 2; ++ks)
          acc[4 + i][fj] = __builtin_amdgcn_mfma_f32_16x16x32_bf16(av[i][ks], bv[fj][ks], acc[4 + i][fj], 0, 0, 0);
    __builtin_amdgcn_s_setprio(0);
    bar_fence();

#pragma unroll
    for (int i = 0; i < 2; ++i)
#pragma unroll
      for (int ks = 0; ks < 2; ++ks) av[i][ks] = rdA(Ac, 6 + i, ks);
    if (t + 1 < nkt) {
      if (t + 2 < nkt) wait_vmcnt<BL>();
      else wait_vmcnt<0>();
    }
    bar_fence();
    lgkm0();
    __builtin_amdgcn_s_setprio(1);
#pragma unroll
    for (int i = 0; i < 2; ++i)
#pragma unroll
      for (int fj = 0; fj < FNW; ++fj)
#pragma unroll
        for (int ks = 0; ks < 2; ++ks)
          acc[6 + i][fj] = __builtin_amdgcn_mfma_f32_16x16x32_bf16(av[i][ks], bv[fj][ks], acc[6 + i][fj], 0, 0, 0);
    __builtin_amdgcn_s_setprio(0);
    bar_fence();
  }

#pragma unroll
  for (int fi = 0; fi < 8; ++fi) {
    const int row0 = bm * 256 + wm * 128 + fi * 16 + ((lane >> 4) << 2);
#pragma unroll
    for (int fj = 0; fj < FNW; ++fj) {
      const int col = bn * BN8 + wn * (BN8 / 4) + fj * 16 + (lane & 15);
      if constexpr (EPI8 == 0) {
        if (col < 512) {
#pragma unroll
          for (int r = 0; r < 4; ++r)
            ((unsigned short*)O0)[(size_t)(row0 + r) * 512 + col] =
                f2bf(acc[fi][fj][r] * qscale);
        } else if (col < 1024) {
#pragma unroll
          for (int r = 0; r < 4; ++r)
            ((unsigned short*)O1)[(size_t)(row0 + r) * 512 + (col - 512)] =
                f2bf(acc[fi][fj][r]);
        } else {
          const int e = col - 1024;
          const int b = row0 >> 11, n0 = row0 & 2047;
          ushort4 u;
          u.x = f2bf(acc[fi][fj][0]);
          u.y = f2bf(acc[fi][fj][1]);
          u.z = f2bf(acc[fi][fj][2]);
          u.w = f2bf(acc[fi][fj][3]);
          *(ushort4*)((unsigned short*)O2 + ((size_t)b * 512 + e) * 2048 + n0) = u;
        }
      } else {
        const float bb = bias[col];
#pragma unroll
        for (int r = 0; r < 4; ++r)
          ((float*)O0)[(size_t)(row0 + r) * 1024 + col] = acc[fi][fj][r] + bb;
      }
    }
  }
}

// ---------------------------------------------------------------------------
// bf16 B^T GEMM (R6-proven 2-phase core): C[M,N] = A[M,K] * B[N,K]^T.
// EPI: 1 sim bf16  2 attn-out bf16.
// TRI: packed lower-triangle decode (aspect-1, 128x128).
// REV: reverse bm (longest-K first when klim).
// ---------------------------------------------------------------------------
template <int EPI, int BM, int BN, int REV, int TRI>
__global__ __launch_bounds__(256) void gemm_bt(
    const unsigned short* __restrict__ A, const unsigned short* __restrict__ B,
    int M, int N, int K, long strideA, long strideB, int klim,
    void* __restrict__ O0, const float* __restrict__ bias) {
  int bm, bn, bz;
  if constexpr (TRI) {
    const int bid = blockIdx.x;
    bm = (int)((sqrtf(8.f * (float)bid + 1.f) - 1.f) * 0.5f);
    while ((bm + 1) * (bm + 2) / 2 <= bid) ++bm;
    while (bm * (bm + 1) / 2 > bid) --bm;
    bn = bid - bm * (bm + 1) / 2;
    bz = blockIdx.y;
  } else {
    bm = REV ? (gridDim.x - 1 - blockIdx.x) : blockIdx.x;
    bn = blockIdx.y;
    bz = blockIdx.z;
  }
  const int tid = threadIdx.x, lane = tid & 63, wave = tid >> 6;
  const int wr = wave >> 1, wc = wave & 1;
  constexpr int FM = BM / 32, FN = BN / 32;
  constexpr int AR = BM / 64, BR = BN / 64;
  constexpr int L = AR + BR;

  __shared__ alignas(16) unsigned short As[3][BM * 32];
  __shared__ alignas(16) unsigned short Bs[3][BN * 32];

  const unsigned short* Ab = A + (size_t)bz * strideA + (size_t)bm * BM * K;
  const unsigned short* Bb = B + (size_t)bz * strideB + (size_t)bn * BN * K;

  const int kmax = klim ? min(K, (bm + 1) * BM) : K;
  const int nkt = kmax >> 5;

  auto stage = [&](int buf, int kt) {
    const int loff = tid * 16;
#pragma unroll
    for (int i = 0; i < AR; ++i) {
      const int o = i * 4096 + loff;
      const int r = o >> 6;
      const int sl = ((o >> 4) & 3) ^ ((r >> 1) & 3);
      __builtin_amdgcn_global_load_lds(
          (const __attribute__((address_space(1))) void*)(
              (const char*)(Ab + (size_t)r * K) + (size_t)kt * 64 + sl * 16),
          (__attribute__((address_space(3))) void*)((char*)As[buf] + o), 16, 0, 0);
    }
#pragma unroll
    for (int i = 0; i < BR; ++i) {
      const int o = i * 4096 + loff;
      const int r = o >> 6;
      const int sl = ((o >> 4) & 3) ^ ((r >> 1) & 3);
      __builtin_amdgcn_global_load_lds(
          (const __attribute__((address_space(1))) void*)(
              (const char*)(Bb + (size_t)r * K) + (size_t)kt * 64 + sl * 16),
          (__attribute__((address_space(3))) void*)((char*)Bs[buf] + o), 16, 0, 0);
    }
  };

  f32x4_t acc[FM][FN] = {};

  stage(0, 0);
  if (nkt > 1) stage(1, 1);
  int cur = 0;
  for (int kt = 0; kt < nkt; ++kt) {
    if (kt + 1 < nkt) wait_vmcnt<L>();
    else wait_vmcnt<0>();
    __builtin_amdgcn_s_barrier();

    bf16x8_t av[FM], bv[FN];
#pragma unroll
    for (int f = 0; f < FM; ++f) {
      const int row = wr * (BM / 2) + f * 16 + (lane & 15);
      const int sp = (lane >> 4) ^ ((row >> 1) & 3);
      av[f] = *(const bf16x8_t*)((const char*)As[cur] + row * 64 + sp * 16);
    }
#pragma unroll
    for (int f = 0; f < FN; ++f) {
      const int row = wc * (BN / 2) + f * 16 + (lane & 15);
      const int sp = (lane >> 4) ^ ((row >> 1) & 3);
      bv[f] = *(const bf16x8_t*)((const char*)Bs[cur] + row * 64 + sp * 16);
    }
    if (kt + 2 < nkt) {
      int nb = cur + 2;
      if (nb >= 3) nb -= 3;
      stage(nb, kt + 2);
    }
    __builtin_amdgcn_s_setprio(1);
#pragma unroll
    for (int fi = 0; fi < FM; ++fi)
#pragma unroll
      for (int fj = 0; fj < FN; ++fj)
        acc[fi][fj] = __builtin_amdgcn_mfma_f32_16x16x32_bf16(av[fi], bv[fj], acc[fi][fj], 0, 0, 0);
    __builtin_amdgcn_s_setprio(0);
    cur = (cur + 1 == 3) ? 0 : cur + 1;
  }

#pragma unroll
  for (int fi = 0; fi < FM; ++fi) {
    const int row_l = wr * (BM / 2) + fi * 16 + ((lane >> 4) << 2);
#pragma unroll
    for (int fj = 0; fj < FN; ++fj) {
      const int col = bn * BN + wc * (BN / 2) + fj * 16 + (lane & 15);
#pragma unroll
      for (int r = 0; r < 4; ++r) {
        const int row = bm * BM + row_l + r;
        float v = acc[fi][fj][r];
        if constexpr (EPI == 1) {
          ((unsigned short*)O0)[(size_t)bz * 2048 * 2048 + (size_t)row * 2048 + col] = f2bf(v);
        } else {
          ((unsigned short*)O0)[(size_t)bz * 2048 * 512 + (size_t)row * 512 + col] = f2bf(v);
        }
      }
    }
  }
}

// ---------------------------------------------------------------------------
extern "C" void kernel_launch(void* const* d_in, const int* in_sizes, int n_in,
                              void* d_out, int out_size, void* d_ws, size_t ws_size,
                              hipStream_t stream) {
  const float* x = (const float*)d_in[0];
  const float* w_qkv = (const float*)d_in[1];
  const float* w_out = (const float*)d_in[2];
  const float* b_out = (const float*)d_in[3];
  float* out = (float*)d_out;

  char* ws = (char*)d_ws;
  size_t off = 0;
  auto alloc = [&](size_t bytes) {
    size_t o = off;
    off += (bytes + 255) & ~(size_t)255;
    return o;
  };
  unsigned short* xb = (unsigned short*)(ws + alloc((size_t)8192 * 1024 * 2));
  unsigned short* wqkvb = (unsigned short*)(ws + alloc((size_t)1536 * 1024 * 2));
  unsigned short* woutb = (unsigned short*)(ws + alloc((size_t)1024 * 512 * 2));
  unsigned short* qb = (unsigned short*)(ws + alloc((size_t)8192 * 512 * 2));
  unsigned short* kb = (unsigned short*)(ws + alloc((size_t)8192 * 512 * 2));
  unsigned short* vtb = (unsigned short*)(ws + alloc((size_t)8192 * 512 * 2));
  unsigned short* sim = (unsigned short*)(ws + alloc((size_t)4 * 2048 * 2048 * 2));
  unsigned short* ao = (unsigned short*)(ws + alloc((size_t)8192 * 512 * 2));

  const float scale = 1.0f / sqrtf(512.0f);

  cvt_all<<<2048, 256, 0, stream>>>(x, xb, 8192 * 1024, w_qkv, wqkvb, 1536 * 1024,
                                    w_out, woutb, 1024 * 512);

  // QKV: 256x192 8-phase, 32x8 = 256 blocks (1/CU), 112KB LDS; V^T epilogue.
  gemm8<0, 192, 1024><<<dim3(32, 8), 512, 65536 + 2 * 192 * 128, stream>>>(
      xb, wqkvb, qb, kb, vtb, nullptr, scale);

  // sim = q*scale @ k^T — packed lower-triangular grid (2-phase core)
  gemm_bt<1, 128, 128, 0, 1><<<dim3(136, 4, 1), 256, 0, stream>>>(
      qb, kb, 2048, 2048, 512, (long)2048 * 512, (long)2048 * 512,
      0, sim, nullptr);

  softmax_causal<<<2048, 256, 0, stream>>>(sim);

  // attn @ v : 64x128 tile, 64-granular K limit, longest-K first
  gemm_bt<2, 64, 128, 1, 0><<<dim3(32, 4, 4), 256, 0, stream>>>(
      sim, vtb, 2048, 512, 2048, (long)2048 * 2048, (long)512 * 2048,
      1, ao, nullptr);

  // proj: 256x128 8-phase, 32x8 = 256 blocks (1/CU), 96KB LDS, fp32+bias.
  gemm8<1, 128, 512><<<dim3(32, 8), 512, 65536 + 2 * 128 * 128, stream>>>(
      ao, woutb, out, nullptr, nullptr, b_out, 0.f);
}